// Round 8
// baseline (213.976 us; speedup 1.0000x reference)
//
#include <hip/hip_runtime.h>

#define MDIM 4096
#define NDIM 4096
#define NCOEF 768
#define ALPHA 16.0f
#define PANEL_U16 (96 * 256 * 8)   // u16 per 256-row panel

typedef __attribute__((ext_vector_type(8))) short bf16x8;
typedef __attribute__((ext_vector_type(4))) float f32x4;

__device__ __forceinline__ unsigned short f2bf(float x) {
    unsigned u = __float_as_uint(x);
    u += 0x7FFFu + ((u >> 16) & 1u);
    return (unsigned short)(u >> 16);
}

__device__ __forceinline__ void glds16(const unsigned short* src, unsigned short* dst) {
    __builtin_amdgcn_global_load_lds(
        (const __attribute__((address_space(1))) void*)src,
        (__attribute__((address_space(3))) void*)dst, 16, 0, 0);
}

// ---- kernel 0: per-coefficient metadata (r, c, scales, dedup) ----
__global__ __launch_bounds__(64) void meta_kernel(
    const int* __restrict__ fidx, const float* __restrict__ dw,
    int* __restrict__ r_m, int* __restrict__ c_m,
    float* __restrict__ su_m, float* __restrict__ sv_m)
{
    __shared__ int idx_s[NCOEF];
    const int t = threadIdx.x;
    #pragma unroll
    for (int j = 0; j < 12; ++j) idx_s[t + j * 64] = fidx[t + j * 64];
    __syncthreads();
    const int p = blockIdx.x * 64 + t;
    const int idx = idx_s[p];
    int keep = 1;                        // last write wins
    #pragma unroll 16
    for (int q = 0; q < NCOEF; ++q)
        keep &= (q <= p) | (idx_s[q] != idx);
    const int r = idx >> 12;
    const int c = idx & (NDIM - 1);
    const float s0 = 0.015625f;              // sqrt(1/4096)
    const float s1 = 0.022097086912079612f;  // sqrt(2/4096)
    r_m[p] = r;
    c_m[p] = c;
    su_m[p] = (r == 0) ? s0 : s1;
    sv_m[p] = (float)keep * ALPHA * dw[p] * ((c == 0) ? s0 : s1);
}

// ---- kernel 1: materialize U,V in 256-row PANEL layout ----
// U[((panel*96 + kc)*256 + row)*8 + pi]; i = panel*256+row, p = kc*8+pi.
// Each BK=64 K-tile (8 kc) of a panel is a contiguous 32 KB slab whose linear
// order equals the k-outer LDS layout.
__global__ __launch_bounds__(256) void fill_uv(
    const int* __restrict__ r_m, const int* __restrict__ c_m,
    const float* __restrict__ su_m, const float* __restrict__ sv_m,
    unsigned short* __restrict__ U, unsigned short* __restrict__ V)
{
    const int b = blockIdx.x;            // (panel*96 + kc)*2 + half
    const int half = b & 1;
    const int pk = b >> 1;               // panel*96 + kc
    const int panel = pk / 96;
    const int kc = pk - panel * 96;
    const int t = threadIdx.x;
    const int rl = (half << 7) + (t >> 1);        // rowLocal 0..255
    const int row = (panel << 8) + rl;            // global i
    const int p0 = (kc << 3) + ((t & 1) << 2);
    const unsigned tt = 2u * (unsigned)row + 1u;
    const float w = 3.14159265358979323846f / 8192.0f;
    unsigned short uo[4], vo[4];
    #pragma unroll
    for (int j = 0; j < 4; ++j) {
        const int p = p0 + j;
        const unsigned nu = (tt * (unsigned)r_m[p]) & 16383u;
        const unsigned nv = (tt * (unsigned)c_m[p]) & 16383u;
        uo[j] = f2bf(su_m[p] * cosf((float)nu * w));
        vo[j] = f2bf(sv_m[p] * cosf((float)nv * w));
    }
    const size_t o = ((size_t)pk * 256 + rl) * 8 + ((t & 1) << 2);
    *(ushort4*)(U + o) = *(const ushort4*)uo;
    *(ushort4*)(V + o) = *(const ushort4*)vo;
}

// ---- kernel 2: out = W + U @ V^T  (M=N=4096, K=768) ----
// 256x256 tile, 8 waves (2x4), BK=64, 12 K-iters, 2-buffer LDS, counted
// vmcnt. Epilogue TRANSPOSES acc through LDS (4 chunks of 64 rows) so W-read
// and out-write are one full 1 KB contiguous row per wave instruction.
__global__ __launch_bounds__(512, 2) void gemm_kernel(
    const float* __restrict__ W,
    const unsigned short* __restrict__ U,
    const unsigned short* __restrict__ V,
    float* __restrict__ out)
{
    __shared__ unsigned short As[2][16384];
    __shared__ unsigned short Bs[2][16384];

    const int tid = threadIdx.x;         // 0..511
    const int lane = tid & 63;
    const int wave = tid >> 6;           // 0..7

    // XCD rect swizzle: 256 blocks, 8 XCDs, 4(by) x 8(bx) rect per XCD.
    const int bid = blockIdx.x;
    const int xcd = bid & 7;
    const int local = bid >> 3;                        // 0..31
    const int by = ((xcd >> 1) << 2) + (local >> 3);   // 0..15
    const int bx = ((xcd & 1) << 3) + (local & 7);     // 0..15
    const int wr = wave >> 2;            // 0..1
    const int wc = wave & 3;             // 0..3
    const int fr = lane & 15;
    const int fks = lane >> 4;

    const unsigned short* uPan = U + (size_t)by * PANEL_U16;
    const unsigned short* vPan = V + (size_t)bx * PANEL_U16;

    f32x4 acc[8][4] = {};

#define STAGE(j, buf) do {                                                  \
        const unsigned short* uS = uPan + (size_t)(j) * 16384;              \
        const unsigned short* vS = vPan + (size_t)(j) * 16384;              \
        _Pragma("unroll")                                                   \
        for (int q = 0; q < 4; ++q) {                                       \
            glds16(uS + (((q << 9) + tid) << 3),                            \
                   &As[buf][(((q << 9) + (wave << 6)) << 3)]);              \
            glds16(vS + (((q << 9) + tid) << 3),                            \
                   &Bs[buf][(((q << 9) + (wave << 6)) << 3)]);              \
        }                                                                   \
    } while (0)

#define COMPUTE(buf) do {                                                   \
        _Pragma("unroll")                                                   \
        for (int s = 0; s < 2; ++s) {                                       \
            const int kb = ((s << 2) + fks) << 8;   /* kc_local*256 */      \
            bf16x8 a[8], b[4];                                              \
            _Pragma("unroll")                                               \
            for (int fm = 0; fm < 8; ++fm)                                  \
                a[fm] = *(const bf16x8*)&As[buf][(kb + wr * 128 + fm * 16 + fr) << 3]; \
            _Pragma("unroll")                                               \
            for (int fn = 0; fn < 4; ++fn)                                  \
                b[fn] = *(const bf16x8*)&Bs[buf][(kb + wc * 64 + fn * 16 + fr) << 3];  \
            _Pragma("unroll")                                               \
            for (int fm = 0; fm < 8; ++fm)                                  \
                _Pragma("unroll")                                           \
                for (int fn = 0; fn < 4; ++fn)                              \
                    acc[fm][fn] = __builtin_amdgcn_mfma_f32_16x16x32_bf16(  \
                        b[fn], a[fm], acc[fm][fn], 0, 0, 0);                \
        }                                                                   \
    } while (0)

    STAGE(0, 0);
    #pragma unroll
    for (int j = 0; j < 12; ++j) {
        if (j < 11) {
            STAGE(j + 1, (j + 1) & 1);
            asm volatile("s_waitcnt vmcnt(8)" ::: "memory");
        } else {
            asm volatile("s_waitcnt vmcnt(0)" ::: "memory");
        }
        __builtin_amdgcn_s_barrier();
        asm volatile("" ::: "memory");
        COMPUTE(j & 1);
        if (j < 11) {
            asm volatile("s_waitcnt lgkmcnt(0)" ::: "memory");
            __builtin_amdgcn_s_barrier();
            asm volatile("" ::: "memory");
        }
    }

    // ---- epilogue: out = W + acc, via LDS transpose ----
    // acc[fm][fn][j] = tile[row = wr*128 + fm*16 + fr][col = wc*64 + fn*16 + fks*4 + j]
    // 4 chunks of 64 rows; LDS stride 260 dwords (even bank spread).
    float* L = (float*)&As[0][0];        // 64*260*4 = 66,560 B, fits staging LDS
    const int bcol = (bx << 8) + lane * 4;
    #pragma unroll 1
    for (int h = 0; h < 4; ++h) {
        __syncthreads();                 // previous LDS use complete
        if (wr == (h >> 1)) {
            const int fmBase = (h & 1) << 2;
            #pragma unroll
            for (int f2 = 0; f2 < 4; ++f2)
                #pragma unroll
                for (int fn = 0; fn < 4; ++fn)
                    *(f32x4*)(L + (f2 * 16 + fr) * 260 + wc * 64 + fn * 16 + fks * 4)
                        = acc[fmBase + f2][fn];
        }
        __syncthreads();
        // coalesced: wave w owns rows w*8..w*8+7; lane -> 16B of the 1 KB row
        #pragma unroll
        for (int i = 0; i < 8; ++i) {
            const int rl = wave * 8 + i;
            const int grow = (by << 8) + h * 64 + rl;
            const size_t o = (size_t)grow * NDIM + bcol;
            const float4 w4 = *(const float4*)(W + o);
            const f32x4 l4 = *(const f32x4*)(L + rl * 260 + lane * 4);
            float4 r4;
            r4.x = w4.x + l4[0];
            r4.y = w4.y + l4[1];
            r4.z = w4.z + l4[2];
            r4.w = w4.w + l4[3];
            *(float4*)(out + o) = r4;
        }
    }
#undef STAGE
#undef COMPUTE
}

extern "C" void kernel_launch(void* const* d_in, const int* in_sizes, int n_in,
                              void* d_out, int out_size, void* d_ws, size_t ws_size,
                              hipStream_t stream) {
    const float* weight = (const float*)d_in[0];
    const float* dw     = (const float*)d_in[1];
    const int*   fidx   = (const int*)d_in[2];
    float* out = (float*)d_out;

    char* ws = (char*)d_ws;
    unsigned short* U = (unsigned short*)ws;                       // 6,291,456 B
    unsigned short* V = (unsigned short*)(ws + 6291456);           // 6,291,456 B
    char* meta = ws + 2 * 6291456;
    int*   r_m  = (int*)(meta);
    int*   c_m  = (int*)(meta + NCOEF * 4);
    float* su_m = (float*)(meta + NCOEF * 8);
    float* sv_m = (float*)(meta + NCOEF * 12);

    meta_kernel<<<12, 64, 0, stream>>>(fidx, dw, r_m, c_m, su_m, sv_m);
    fill_uv<<<16 * 96 * 2, 256, 0, stream>>>(r_m, c_m, su_m, sv_m, U, V);
    gemm_kernel<<<256, 512, 0, stream>>>(weight, U, V, out);
}

// Round 9
// 69.028 us; speedup vs baseline: 3.0998x; 3.0998x over previous
//
#include <hip/hip_runtime.h>

#define MDIM 4096
#define NDIM 4096
#define NCOEF 768
#define ALPHA 16.0f
#define PANEL_U16 (96 * 256 * 8)   // u16 per 256-row panel

typedef __attribute__((ext_vector_type(8))) short bf16x8;
typedef __attribute__((ext_vector_type(4))) float f32x4;

__device__ __forceinline__ unsigned short f2bf(float x) {
    unsigned u = __float_as_uint(x);
    u += 0x7FFFu + ((u >> 16) & 1u);
    return (unsigned short)(u >> 16);
}

__device__ __forceinline__ void glds16(const unsigned short* src, unsigned short* dst) {
    __builtin_amdgcn_global_load_lds(
        (const __attribute__((address_space(1))) void*)src,
        (__attribute__((address_space(3))) void*)dst, 16, 0, 0);
}

// ---- kernel 0: per-coefficient metadata (r, c, scales, dedup) ----
__global__ __launch_bounds__(64) void meta_kernel(
    const int* __restrict__ fidx, const float* __restrict__ dw,
    int* __restrict__ r_m, int* __restrict__ c_m,
    float* __restrict__ su_m, float* __restrict__ sv_m)
{
    __shared__ int idx_s[NCOEF];
    const int t = threadIdx.x;
    #pragma unroll
    for (int j = 0; j < 12; ++j) idx_s[t + j * 64] = fidx[t + j * 64];
    __syncthreads();
    const int p = blockIdx.x * 64 + t;
    const int idx = idx_s[p];
    int keep = 1;                        // last write wins
    #pragma unroll 16
    for (int q = 0; q < NCOEF; ++q)
        keep &= (q <= p) | (idx_s[q] != idx);
    const int r = idx >> 12;
    const int c = idx & (NDIM - 1);
    const float s0 = 0.015625f;              // sqrt(1/4096)
    const float s1 = 0.022097086912079612f;  // sqrt(2/4096)
    r_m[p] = r;
    c_m[p] = c;
    su_m[p] = (r == 0) ? s0 : s1;
    sv_m[p] = (float)keep * ALPHA * dw[p] * ((c == 0) ? s0 : s1);
}

// ---- kernel 1: materialize U,V in 256-row PANEL layout ----
// U[((panel*96 + kc)*256 + row)*8 + pi]; i = panel*256+row, p = kc*8+pi.
// Each BK=64 K-tile (8 kc) of a panel is a contiguous 32 KB slab whose linear
// order equals the k-outer LDS layout.
__global__ __launch_bounds__(256) void fill_uv(
    const int* __restrict__ r_m, const int* __restrict__ c_m,
    const float* __restrict__ su_m, const float* __restrict__ sv_m,
    unsigned short* __restrict__ U, unsigned short* __restrict__ V)
{
    const int b = blockIdx.x;            // (panel*96 + kc)*2 + half
    const int half = b & 1;
    const int pk = b >> 1;               // panel*96 + kc
    const int panel = pk / 96;
    const int kc = pk - panel * 96;
    const int t = threadIdx.x;
    const int rl = (half << 7) + (t >> 1);        // rowLocal 0..255
    const int row = (panel << 8) + rl;            // global i
    const int p0 = (kc << 3) + ((t & 1) << 2);
    const unsigned tt = 2u * (unsigned)row + 1u;
    const float w = 3.14159265358979323846f / 8192.0f;
    unsigned short uo[4], vo[4];
    #pragma unroll
    for (int j = 0; j < 4; ++j) {
        const int p = p0 + j;
        const unsigned nu = (tt * (unsigned)r_m[p]) & 16383u;
        const unsigned nv = (tt * (unsigned)c_m[p]) & 16383u;
        uo[j] = f2bf(su_m[p] * cosf((float)nu * w));
        vo[j] = f2bf(sv_m[p] * cosf((float)nv * w));
    }
    const size_t o = ((size_t)pk * 256 + rl) * 8 + ((t & 1) << 2);
    *(ushort4*)(U + o) = *(const ushort4*)uo;
    *(ushort4*)(V + o) = *(const ushort4*)vo;
}

// ---- kernel 2: out = W + U @ V^T  (M=N=4096, K=768) ----
// 256x256 tile, 8 waves (2x4), BK=64, 12 K-iters, 2-buffer LDS, counted
// vmcnt. Epilogue transposes acc through LDS (4 chunks of 64 rows, FULLY
// UNROLLED -> static acc indices, no spill) so W-read and out-write are one
// 1 KB contiguous row per wave instruction. launch_bounds(512,1): 128 KB LDS
// forces 1 block/CU anyway; VGPR cap 256 keeps acc in registers.
__global__ __launch_bounds__(512, 1) void gemm_kernel(
    const float* __restrict__ W,
    const unsigned short* __restrict__ U,
    const unsigned short* __restrict__ V,
    float* __restrict__ out)
{
    __shared__ unsigned short SM[65536];   // 128 KB: As dbuf | Bs dbuf / L
    unsigned short* const As = SM;               // [buf*16384 + ...]
    unsigned short* const Bs = SM + 32768;

    const int tid = threadIdx.x;         // 0..511
    const int lane = tid & 63;
    const int wave = tid >> 6;           // 0..7

    // XCD rect swizzle: 256 blocks, 8 XCDs, 4(by) x 8(bx) rect per XCD.
    const int bid = blockIdx.x;
    const int xcd = bid & 7;
    const int local = bid >> 3;                        // 0..31
    const int by = ((xcd >> 1) << 2) + (local >> 3);   // 0..15
    const int bx = ((xcd & 1) << 3) + (local & 7);     // 0..15
    const int wr = wave >> 2;            // 0..1
    const int wc = wave & 3;             // 0..3
    const int fr = lane & 15;
    const int fks = lane >> 4;

    const unsigned short* uPan = U + (size_t)by * PANEL_U16;
    const unsigned short* vPan = V + (size_t)bx * PANEL_U16;

    f32x4 acc[8][4] = {};

#define STAGE(j, buf) do {                                                  \
        const unsigned short* uS = uPan + (size_t)(j) * 16384;              \
        const unsigned short* vS = vPan + (size_t)(j) * 16384;              \
        _Pragma("unroll")                                                   \
        for (int q = 0; q < 4; ++q) {                                       \
            glds16(uS + (((q << 9) + tid) << 3),                            \
                   &As[(buf) * 16384 + (((q << 9) + (wave << 6)) << 3)]);   \
            glds16(vS + (((q << 9) + tid) << 3),                            \
                   &Bs[(buf) * 16384 + (((q << 9) + (wave << 6)) << 3)]);   \
        }                                                                   \
    } while (0)

#define COMPUTE(buf) do {                                                   \
        _Pragma("unroll")                                                   \
        for (int s = 0; s < 2; ++s) {                                       \
            const int kb = ((s << 2) + fks) << 8;   /* kc_local*256 */      \
            bf16x8 a[8], b[4];                                              \
            _Pragma("unroll")                                               \
            for (int fm = 0; fm < 8; ++fm)                                  \
                a[fm] = *(const bf16x8*)&As[(buf) * 16384 +                 \
                            ((kb + wr * 128 + fm * 16 + fr) << 3)];         \
            _Pragma("unroll")                                               \
            for (int fn = 0; fn < 4; ++fn)                                  \
                b[fn] = *(const bf16x8*)&Bs[(buf) * 16384 +                 \
                            ((kb + wc * 64 + fn * 16 + fr) << 3)];          \
            _Pragma("unroll")                                               \
            for (int fm = 0; fm < 8; ++fm)                                  \
                _Pragma("unroll")                                           \
                for (int fn = 0; fn < 4; ++fn)                              \
                    acc[fm][fn] = __builtin_amdgcn_mfma_f32_16x16x32_bf16(  \
                        b[fn], a[fm], acc[fm][fn], 0, 0, 0);                \
        }                                                                   \
    } while (0)

    STAGE(0, 0);
    #pragma unroll
    for (int j = 0; j < 12; ++j) {
        if (j < 11) {
            STAGE(j + 1, (j + 1) & 1);
            asm volatile("s_waitcnt vmcnt(8)" ::: "memory");
        } else {
            asm volatile("s_waitcnt vmcnt(0)" ::: "memory");
        }
        __builtin_amdgcn_s_barrier();
        asm volatile("" ::: "memory");
        COMPUTE(j & 1);
        if (j < 11) {
            asm volatile("s_waitcnt lgkmcnt(0)" ::: "memory");
            __builtin_amdgcn_s_barrier();
            asm volatile("" ::: "memory");
        }
    }

    // ---- epilogue: out = W + acc, via LDS transpose (fully unrolled) ----
    // acc[fm][fn][j] = tile[wr*128 + fm*16 + fr][wc*64 + fn*16 + fks*4 + j]
    // 4 chunks of 64 rows; LDS row stride 260 dwords (bank spread).
    float* const L = (float*)SM;        // 64*260*4 = 66,560 B < 128 KB
    const int bcol = (bx << 8) + lane * 4;
    #pragma unroll
    for (int h = 0; h < 4; ++h) {
        __syncthreads();                 // previous LDS use complete
        if (wr == (h >> 1)) {
            #pragma unroll
            for (int f2 = 0; f2 < 4; ++f2)
                #pragma unroll
                for (int fn = 0; fn < 4; ++fn)
                    *(f32x4*)(L + (f2 * 16 + fr) * 260 + wc * 64 + fn * 16 + fks * 4)
                        = acc[(h & 1) * 4 + f2][fn];
        }
        __syncthreads();
        // coalesced: wave w owns rows w*8..w*8+7; lane -> 16B of the 1 KB row
        #pragma unroll
        for (int i = 0; i < 8; ++i) {
            const int rl = wave * 8 + i;
            const int grow = (by << 8) + h * 64 + rl;
            const size_t o = (size_t)grow * NDIM + bcol;
            const float4 w4 = *(const float4*)(W + o);
            const f32x4 l4 = *(const f32x4*)(L + rl * 260 + lane * 4);
            float4 r4;
            r4.x = w4.x + l4[0];
            r4.y = w4.y + l4[1];
            r4.z = w4.z + l4[2];
            r4.w = w4.w + l4[3];
            *(float4*)(out + o) = r4;
        }
    }
#undef STAGE
#undef COMPUTE
}

extern "C" void kernel_launch(void* const* d_in, const int* in_sizes, int n_in,
                              void* d_out, int out_size, void* d_ws, size_t ws_size,
                              hipStream_t stream) {
    const float* weight = (const float*)d_in[0];
    const float* dw     = (const float*)d_in[1];
    const int*   fidx   = (const int*)d_in[2];
    float* out = (float*)d_out;

    char* ws = (char*)d_ws;
    unsigned short* U = (unsigned short*)ws;                       // 6,291,456 B
    unsigned short* V = (unsigned short*)(ws + 6291456);           // 6,291,456 B
    char* meta = ws + 2 * 6291456;
    int*   r_m  = (int*)(meta);
    int*   c_m  = (int*)(meta + NCOEF * 4);
    float* su_m = (float*)(meta + NCOEF * 8);
    float* sv_m = (float*)(meta + NCOEF * 12);

    meta_kernel<<<12, 64, 0, stream>>>(fidx, dw, r_m, c_m, su_m, sv_m);
    fill_uv<<<16 * 96 * 2, 256, 0, stream>>>(r_m, c_m, su_m, sv_m, U, V);
    gemm_kernel<<<256, 512, 0, stream>>>(weight, U, V, out);
}

// Round 10
// 64.006 us; speedup vs baseline: 3.3431x; 1.0785x over previous
//
#include <hip/hip_runtime.h>

#define MDIM 4096
#define NDIM 4096
#define NCOEF 768
#define ALPHA 16.0f
#define PANEL_U16 (96 * 256 * 8)   // u16 per 256-row panel

typedef __attribute__((ext_vector_type(8))) short bf16x8;
typedef __attribute__((ext_vector_type(4))) float f32x4;

__device__ __forceinline__ unsigned short f2bf(float x) {
    unsigned u = __float_as_uint(x);
    u += 0x7FFFu + ((u >> 16) & 1u);
    return (unsigned short)(u >> 16);
}

__device__ __forceinline__ void glds16(const unsigned short* src, unsigned short* dst) {
    __builtin_amdgcn_global_load_lds(
        (const __attribute__((address_space(1))) void*)src,
        (__attribute__((address_space(3))) void*)dst, 16, 0, 0);
}

// ---- kernel 0: per-coefficient metadata (r, c, scales, dedup) ----
__global__ __launch_bounds__(64) void meta_kernel(
    const int* __restrict__ fidx, const float* __restrict__ dw,
    int* __restrict__ r_m, int* __restrict__ c_m,
    float* __restrict__ su_m, float* __restrict__ sv_m)
{
    __shared__ int idx_s[NCOEF];
    const int t = threadIdx.x;
    #pragma unroll
    for (int j = 0; j < 12; ++j) idx_s[t + j * 64] = fidx[t + j * 64];
    __syncthreads();
    const int p = blockIdx.x * 64 + t;
    const int idx = idx_s[p];
    int keep = 1;                        // last write wins
    #pragma unroll 16
    for (int q = 0; q < NCOEF; ++q)
        keep &= (q <= p) | (idx_s[q] != idx);
    const int r = idx >> 12;
    const int c = idx & (NDIM - 1);
    const float s0 = 0.015625f;              // sqrt(1/4096)
    const float s1 = 0.022097086912079612f;  // sqrt(2/4096)
    r_m[p] = r;
    c_m[p] = c;
    su_m[p] = (r == 0) ? s0 : s1;
    sv_m[p] = (float)keep * ALPHA * dw[p] * ((c == 0) ? s0 : s1);
}

// ---- kernel 1: materialize U,V in 256-row PANEL layout ----
// U[((panel*96 + kc)*256 + row)*8 + pi]; i = panel*256+row, p = kc*8+pi.
// cos via v_cos_f32 (revolutions): cos(pi*n/8192) = cos(2pi * n/16384),
// n integer-exact in [0,16384) -> |1 ulp| error, far below bf16 rounding.
__global__ __launch_bounds__(256) void fill_uv(
    const int* __restrict__ r_m, const int* __restrict__ c_m,
    const float* __restrict__ su_m, const float* __restrict__ sv_m,
    unsigned short* __restrict__ U, unsigned short* __restrict__ V)
{
    const int b = blockIdx.x;            // (panel*96 + kc)*2 + half
    const int half = b & 1;
    const int pk = b >> 1;               // panel*96 + kc
    const int panel = pk / 96;
    const int kc = pk - panel * 96;
    const int t = threadIdx.x;
    const int rl = (half << 7) + (t >> 1);        // rowLocal 0..255
    const int row = (panel << 8) + rl;            // global i
    const int p0 = (kc << 3) + ((t & 1) << 2);
    const unsigned tt = 2u * (unsigned)row + 1u;
    const float wrev = 1.0f / 16384.0f;
    unsigned short uo[4], vo[4];
    #pragma unroll
    for (int j = 0; j < 4; ++j) {
        const int p = p0 + j;
        const unsigned nu = (tt * (unsigned)r_m[p]) & 16383u;
        const unsigned nv = (tt * (unsigned)c_m[p]) & 16383u;
        uo[j] = f2bf(su_m[p] * __builtin_amdgcn_cosf((float)nu * wrev));
        vo[j] = f2bf(sv_m[p] * __builtin_amdgcn_cosf((float)nv * wrev));
    }
    const size_t o = ((size_t)pk * 256 + rl) * 8 + ((t & 1) << 2);
    *(ushort4*)(U + o) = *(const ushort4*)uo;
    *(ushort4*)(V + o) = *(const ushort4*)vo;
}

// ---- kernel 2: out = W + U @ V^T  (M=N=4096, K=768) ----
// 256x256 tile, 8 waves (2x4), BK=32, 24 K-iters. FOUR 32 KB LDS buffers,
// depth-2 prefetch, ONE barrier per iter, counted vmcnt(8). Safety: staged
// buffer is >= 3 ahead of any read buffer; collective barrier bounds wave
// skew to < 1 iter. Epilogue: pipelined LDS transpose (two 33 KB regions,
// 8 chunks of 32 rows, 1 barrier/chunk) + W register-prefetch depth 1 ->
// coalesced 1 KB-row streams for W-read and out-write.
__global__ __launch_bounds__(512, 1) void gemm_kernel(
    const float* __restrict__ W,
    const unsigned short* __restrict__ U,
    const unsigned short* __restrict__ V,
    float* __restrict__ out)
{
    __shared__ unsigned short SM[65536];   // 128 KB
    unsigned short* const As = SM;               // buf b at b*8192 u16
    unsigned short* const Bs = SM + 32768;

    const int tid = threadIdx.x;         // 0..511
    const int lane = tid & 63;
    const int wave = tid >> 6;           // 0..7

    // XCD rect swizzle: 256 blocks, 8 XCDs, 4(by) x 8(bx) rect per XCD.
    const int bid = blockIdx.x;
    const int xcd = bid & 7;
    const int local = bid >> 3;                        // 0..31
    const int by = ((xcd >> 1) << 2) + (local >> 3);   // 0..15
    const int bx = ((xcd & 1) << 3) + (local & 7);     // 0..15
    const int wr = wave >> 2;            // 0..1
    const int wc = wave & 3;             // 0..3
    const int fr = lane & 15;
    const int fks = lane >> 4;

    const unsigned short* uPan = U + (size_t)by * PANEL_U16;
    const unsigned short* vPan = V + (size_t)bx * PANEL_U16;

    f32x4 acc[8][4] = {};

    // fragment offsets (u16): chunk = fks*256 + row, 8 u16 per chunk
    const int aO = (((fks << 8) + wr * 128 + fr) << 3);
    const int bO = (((fks << 8) + wc * 64 + fr) << 3);

#define STAGE(j, buf) do {                                                  \
        const unsigned short* uS = uPan + (size_t)(j) * 8192;               \
        const unsigned short* vS = vPan + (size_t)(j) * 8192;               \
        glds16(uS + ((size_t)tid << 3),        &As[(buf) * 8192 + (wave << 9)]); \
        glds16(uS + 4096 + ((size_t)tid << 3), &As[(buf) * 8192 + 4096 + (wave << 9)]); \
        glds16(vS + ((size_t)tid << 3),        &Bs[(buf) * 8192 + (wave << 9)]); \
        glds16(vS + 4096 + ((size_t)tid << 3), &Bs[(buf) * 8192 + 4096 + (wave << 9)]); \
    } while (0)

#define COMPUTE(buf) do {                                                   \
        bf16x8 a[8], b[4];                                                  \
        _Pragma("unroll")                                                   \
        for (int fm = 0; fm < 8; ++fm)                                      \
            a[fm] = *(const bf16x8*)&As[(buf) * 8192 + aO + (fm << 7)];     \
        _Pragma("unroll")                                                   \
        for (int fn = 0; fn < 4; ++fn)                                      \
            b[fn] = *(const bf16x8*)&Bs[(buf) * 8192 + bO + (fn << 7)];     \
        _Pragma("unroll")                                                   \
        for (int fm = 0; fm < 8; ++fm)                                      \
            _Pragma("unroll")                                               \
            for (int fn = 0; fn < 4; ++fn)                                  \
                acc[fm][fn] = __builtin_amdgcn_mfma_f32_16x16x32_bf16(      \
                    b[fn], a[fm], acc[fm][fn], 0, 0, 0);                    \
    } while (0)

    STAGE(0, 0);
    STAGE(1, 1);
    #pragma unroll
    for (int j = 0; j < 24; ++j) {
        if (j < 22) {
            STAGE(j + 2, (j + 2) & 3);
            asm volatile("s_waitcnt vmcnt(8)" ::: "memory");
        } else if (j == 22) {
            asm volatile("s_waitcnt vmcnt(4)" ::: "memory");
        } else {
            asm volatile("s_waitcnt vmcnt(0)" ::: "memory");
        }
        __builtin_amdgcn_s_barrier();
        asm volatile("" ::: "memory");
        COMPUTE(j & 3);
    }

    // ---- epilogue: out = W + acc, pipelined LDS transpose ----
    // acc[fm][fn][j] = tile[wr*128 + fm*16 + fr][wc*64 + fn*16 + fks*4 + j]
    // chunk c (0..7): local rows 32c..32c+31, owner wr == c>>2, fmBase=(c&3)*2.
    // L region (c&1): 32 rows x 258 f32 = 33 KB; regions at f32 offset 0/8256.
    // Note: L0 bytes [0,33024) overlap only A-bufs 0/1, never buf 3 (last
    // compute) or buf 2 (guarded by barrier collectivity).
    float* const L = (float*)SM;
    const int bcol = (bx << 8) + (lane << 2);
    const int erowBase = (by << 8);
    float4 wpre[2][4];

    // prologue: chunk 0
    #pragma unroll
    for (int i = 0; i < 4; ++i)
        wpre[0][i] = *(const float4*)(
            W + (size_t)(erowBase + wave * 4 + i) * NDIM + bcol);
    if (wr == 0) {
        #pragma unroll
        for (int f2 = 0; f2 < 2; ++f2)
            #pragma unroll
            for (int fn = 0; fn < 4; ++fn)
                *(f32x4*)(L + (f2 * 16 + fr) * 258 + wc * 64 + fn * 16 + fks * 4)
                    = acc[f2][fn];
    }
    #pragma unroll
    for (int c = 0; c < 8; ++c) {
        __syncthreads();
        if (c < 7) {
            #pragma unroll
            for (int i = 0; i < 4; ++i)
                wpre[(c + 1) & 1][i] = *(const float4*)(
                    W + (size_t)(erowBase + (c + 1) * 32 + wave * 4 + i) * NDIM + bcol);
            if (wr == ((c + 1) >> 2)) {
                #pragma unroll
                for (int f2 = 0; f2 < 2; ++f2)
                    #pragma unroll
                    for (int fn = 0; fn < 4; ++fn)
                        *(f32x4*)(L + ((c + 1) & 1) * 8256
                                  + (f2 * 16 + fr) * 258 + wc * 64 + fn * 16 + fks * 4)
                            = acc[((c + 1) & 3) * 2 + f2][fn];
            }
        }
        #pragma unroll
        for (int i = 0; i < 4; ++i) {
            const int rl = wave * 4 + i;
            const size_t o = (size_t)(erowBase + c * 32 + rl) * NDIM + bcol;
            const f32x4 l4 = *(const f32x4*)(L + (c & 1) * 8256 + rl * 258 + (lane << 2));
            float4 r4;
            r4.x = wpre[c & 1][i].x + l4[0];
            r4.y = wpre[c & 1][i].y + l4[1];
            r4.z = wpre[c & 1][i].z + l4[2];
            r4.w = wpre[c & 1][i].w + l4[3];
            *(float4*)(out + o) = r4;
        }
    }
#undef STAGE
#undef COMPUTE
}

extern "C" void kernel_launch(void* const* d_in, const int* in_sizes, int n_in,
                              void* d_out, int out_size, void* d_ws, size_t ws_size,
                              hipStream_t stream) {
    const float* weight = (const float*)d_in[0];
    const float* dw     = (const float*)d_in[1];
    const int*   fidx   = (const int*)d_in[2];
    float* out = (float*)d_out;

    char* ws = (char*)d_ws;
    unsigned short* U = (unsigned short*)ws;                       // 6,291,456 B
    unsigned short* V = (unsigned short*)(ws + 6291456);           // 6,291,456 B
    char* meta = ws + 2 * 6291456;
    int*   r_m  = (int*)(meta);
    int*   c_m  = (int*)(meta + NCOEF * 4);
    float* su_m = (float*)(meta + NCOEF * 8);
    float* sv_m = (float*)(meta + NCOEF * 12);

    meta_kernel<<<12, 64, 0, stream>>>(fidx, dw, r_m, c_m, su_m, sv_m);
    fill_uv<<<16 * 96 * 2, 256, 0, stream>>>(r_m, c_m, su_m, sv_m, U, V);
    gemm_kernel<<<256, 512, 0, stream>>>(weight, U, V, out);
}

// Round 11
// 51.288 us; speedup vs baseline: 4.1721x; 1.2480x over previous
//
#include <hip/hip_runtime.h>

#define MDIM 4096
#define NDIM 4096
#define NCOEF 768
#define ALPHA 16.0f
#define PANEL_U16 (96 * 256 * 8)   // u16 per 256-row panel

typedef __attribute__((ext_vector_type(8))) short bf16x8;
typedef __attribute__((ext_vector_type(4))) float f32x4;

__device__ __forceinline__ unsigned short f2bf(float x) {
    unsigned u = __float_as_uint(x);
    u += 0x7FFFu + ((u >> 16) & 1u);
    return (unsigned short)(u >> 16);
}

__device__ __forceinline__ void glds16(const unsigned short* src, unsigned short* dst) {
    __builtin_amdgcn_global_load_lds(
        (const __attribute__((address_space(1))) void*)src,
        (__attribute__((address_space(3))) void*)dst, 16, 0, 0);
}

// ---- kernel 1 (meta FUSED): materialize U,V in 256-row PANEL layout ----
// U[((panel*96 + kc)*256 + row)*8 + pi]; i = panel*256+row, p = kc*8+pi.
// Dedup (last-write-wins) computed per block: 32 threads per coef scan 24 q's.
// cos via v_cos_f32 (revolutions), integer-exact range reduction.
__global__ __launch_bounds__(256) void fill_uv(
    const int* __restrict__ fidx, const float* __restrict__ dw,
    unsigned short* __restrict__ U, unsigned short* __restrict__ V)
{
    __shared__ int idx_s[NCOEF];
    __shared__ int dup[8];
    const int b = blockIdx.x;            // (panel*96 + kc)*2 + half
    const int half = b & 1;
    const int pk = b >> 1;               // panel*96 + kc
    const int panel = pk / 96;
    const int kc = pk - panel * 96;
    const int t = threadIdx.x;
    #pragma unroll
    for (int j = 0; j < 3; ++j) idx_s[t + (j << 8)] = fidx[t + (j << 8)];
    if (t < 8) dup[t] = 0;
    __syncthreads();
    {   // dedup for this block's 8 coefs
        const int ci = t >> 5;                    // 0..7
        const int pci = (kc << 3) + ci;
        const int myidx = idx_s[pci];
        const int q0 = (t & 31) * 24;             // 32 segments x 24 = 768
        int found = 0;
        #pragma unroll
        for (int s = 0; s < 24; ++s) {
            const int q = q0 + s;
            found |= (q > pci) & (idx_s[q] == myidx);
        }
        if (found) dup[ci] = 1;                   // benign same-value race
    }
    __syncthreads();
    const int rl = (half << 7) + (t >> 1);        // rowLocal 0..255
    const int row = (panel << 8) + rl;            // global i
    const int p0 = (kc << 3) + ((t & 1) << 2);
    const unsigned tt = 2u * (unsigned)row + 1u;
    const float wrev = 1.0f / 16384.0f;
    const float s0 = 0.015625f;                   // sqrt(1/4096)
    const float s1 = 0.022097086912079612f;       // sqrt(2/4096)
    unsigned short uo[4], vo[4];
    #pragma unroll
    for (int j = 0; j < 4; ++j) {
        const int p = p0 + j;
        const int idx = idx_s[p];
        const int r = idx >> 12;
        const int c = idx & (NDIM - 1);
        const float su = (r == 0) ? s0 : s1;
        const float sv = (dup[p - (kc << 3)] ? 0.0f : 1.0f) * ALPHA * dw[p]
                         * ((c == 0) ? s0 : s1);
        const unsigned nu = (tt * (unsigned)r) & 16383u;
        const unsigned nv = (tt * (unsigned)c) & 16383u;
        uo[j] = f2bf(su * __builtin_amdgcn_cosf((float)nu * wrev));
        vo[j] = f2bf(sv * __builtin_amdgcn_cosf((float)nv * wrev));
    }
    const size_t o = ((size_t)pk * 256 + rl) * 8 + ((t & 1) << 2);
    *(ushort4*)(U + o) = *(const ushort4*)uo;
    *(ushort4*)(V + o) = *(const ushort4*)vo;
}

// ---- kernel 2: out = W + U @ V^T  (M=N=4096, K=768) ----
// 256x256 tile, 8 waves (2x4), BK=32, 24 K-iters, 4 LDS buffers, depth-2
// prefetch, ONE barrier/iter, counted vmcnt. W for epilogue chunks 0-1 is
// loaded DURING the K-loop (j==21; vmcnt counts include the 8 extra loads),
// spreading HBM reads into the compute phase. Epilogue: pipelined LDS
// transpose with RAW barriers (lgkmcnt-only drain) so W loads for chunks
// 2-7 stay in flight across barriers (issued 2 chunks ahead).
__global__ __launch_bounds__(512, 1) void gemm_kernel(
    const float* __restrict__ W,
    const unsigned short* __restrict__ U,
    const unsigned short* __restrict__ V,
    float* __restrict__ out)
{
    __shared__ unsigned short SM[65536];   // 128 KB
    unsigned short* const As = SM;               // buf b at b*8192 u16
    unsigned short* const Bs = SM + 32768;

    const int tid = threadIdx.x;         // 0..511
    const int lane = tid & 63;
    const int wave = tid >> 6;           // 0..7

    // XCD rect swizzle: 256 blocks, 8 XCDs, 4(by) x 8(bx) rect per XCD.
    const int bid = blockIdx.x;
    const int xcd = bid & 7;
    const int local = bid >> 3;                        // 0..31
    const int by = ((xcd >> 1) << 2) + (local >> 3);   // 0..15
    const int bx = ((xcd & 1) << 3) + (local & 7);     // 0..15
    const int wr = wave >> 2;            // 0..1
    const int wc = wave & 3;             // 0..3
    const int fr = lane & 15;
    const int fks = lane >> 4;

    const unsigned short* uPan = U + (size_t)by * PANEL_U16;
    const unsigned short* vPan = V + (size_t)bx * PANEL_U16;

    f32x4 acc[8][4] = {};

    // fragment offsets (u16): chunk = fks*256 + row, 8 u16 per chunk
    const int aO = (((fks << 8) + wr * 128 + fr) << 3);
    const int bO = (((fks << 8) + wc * 64 + fr) << 3);

    // epilogue coords (needed early for in-loop W prefetch)
    const int bcol = (bx << 8) + (lane << 2);
    const int erowBase = (by << 8);
    float4 wA[2][4];   // W for chunks 0-1, loaded in K-loop
    float4 wB[2][4];   // W for chunks 2-7, rotating

#define STAGE(j, buf) do {                                                  \
        const unsigned short* uS = uPan + (size_t)(j) * 8192;               \
        const unsigned short* vS = vPan + (size_t)(j) * 8192;               \
        glds16(uS + ((size_t)tid << 3),        &As[(buf) * 8192 + (wave << 9)]); \
        glds16(uS + 4096 + ((size_t)tid << 3), &As[(buf) * 8192 + 4096 + (wave << 9)]); \
        glds16(vS + ((size_t)tid << 3),        &Bs[(buf) * 8192 + (wave << 9)]); \
        glds16(vS + 4096 + ((size_t)tid << 3), &Bs[(buf) * 8192 + 4096 + (wave << 9)]); \
    } while (0)

#define COMPUTE(buf) do {                                                   \
        bf16x8 a[8], b[4];                                                  \
        _Pragma("unroll")                                                   \
        for (int fm = 0; fm < 8; ++fm)                                      \
            a[fm] = *(const bf16x8*)&As[(buf) * 8192 + aO + (fm << 7)];     \
        _Pragma("unroll")                                                   \
        for (int fn = 0; fn < 4; ++fn)                                      \
            b[fn] = *(const bf16x8*)&Bs[(buf) * 8192 + bO + (fn << 7)];     \
        _Pragma("unroll")                                                   \
        for (int fm = 0; fm < 8; ++fm)                                      \
            _Pragma("unroll")                                               \
            for (int fn = 0; fn < 4; ++fn)                                  \
                acc[fm][fn] = __builtin_amdgcn_mfma_f32_16x16x32_bf16(      \
                    b[fn], a[fm], acc[fm][fn], 0, 0, 0);                    \
    } while (0)

    STAGE(0, 0);
    STAGE(1, 1);
    #pragma unroll
    for (int j = 0; j < 24; ++j) {
        if (j < 22) STAGE(j + 2, (j + 2) & 3);
        if (j == 21) {
            // W prefetch for epilogue chunks 0-1 (8 loads, counted below)
            #pragma unroll
            for (int cc = 0; cc < 2; ++cc)
                #pragma unroll
                for (int i = 0; i < 4; ++i)
                    wA[cc][i] = *(const float4*)(
                        W + (size_t)(erowBase + cc * 32 + wave * 4 + i) * NDIM + bcol);
        }
        // exact counts: buf j must be complete; newer stage loads + 8 W
        // loads (from j>=21) stay in flight.
        if (j < 21)       asm volatile("s_waitcnt vmcnt(8)"  ::: "memory");
        else if (j == 21) asm volatile("s_waitcnt vmcnt(16)" ::: "memory");
        else if (j == 22) asm volatile("s_waitcnt vmcnt(12)" ::: "memory");
        else              asm volatile("s_waitcnt vmcnt(8)"  ::: "memory");
        __builtin_amdgcn_s_barrier();
        asm volatile("" ::: "memory");
        COMPUTE(j & 3);
    }

    // ---- epilogue: out = W + acc, pipelined LDS transpose ----
    // acc[fm][fn][j] = tile[wr*128 + fm*16 + fr][wc*64 + fn*16 + fks*4 + j]
    // chunk c (0..7): rows 32c..32c+31, owner wr == c>>2, acc pair (c&3)*2.
    // L regions (c&1): 32 rows x 258 f32 = 33 KB at f32 offsets 0 / 8256.
    // Region0 overlaps As bufs 0-2 only; region1 first written after the
    // first epilogue barrier (all waves past COMPUTE(3)) -> safe.
    float* const L = (float*)SM;
    if (wr == 0) {   // prologue: chunk 0 into region 0
        #pragma unroll
        for (int f2 = 0; f2 < 2; ++f2)
            #pragma unroll
            for (int fn = 0; fn < 4; ++fn)
                *(f32x4*)(L + (f2 * 16 + fr) * 258 + wc * 64 + fn * 16 + fks * 4)
                    = acc[f2][fn];
    }
    #pragma unroll
    for (int c = 0; c < 8; ++c) {
        asm volatile("s_waitcnt lgkmcnt(0)" ::: "memory");
        __builtin_amdgcn_s_barrier();
        asm volatile("" ::: "memory");
        if (c < 7) {
            if (wr == ((c + 1) >> 2)) {
                #pragma unroll
                for (int f2 = 0; f2 < 2; ++f2)
                    #pragma unroll
                    for (int fn = 0; fn < 4; ++fn)
                        *(f32x4*)(L + ((c + 1) & 1) * 8256
                                  + (f2 * 16 + fr) * 258 + wc * 64 + fn * 16 + fks * 4)
                            = acc[((c + 1) & 3) * 2 + f2][fn];
            }
        }
        #pragma unroll
        for (int i = 0; i < 4; ++i) {
            const int rl2 = wave * 4 + i;
            const size_t o = (size_t)(erowBase + c * 32 + rl2) * NDIM + bcol;
            const f32x4 l4 = *(const f32x4*)(L + (c & 1) * 8256 + rl2 * 258 + (lane << 2));
            const float4 w4 = (c < 2) ? wA[c][i] : wB[c & 1][i];
            float4 r4;
            r4.x = w4.x + l4[0];
            r4.y = w4.y + l4[1];
            r4.z = w4.z + l4[2];
            r4.w = w4.w + l4[3];
            *(float4*)(out + o) = r4;
        }
        if (c < 6) {   // W for chunk c+2, stays in flight across barriers
            #pragma unroll
            for (int i = 0; i < 4; ++i)
                wB[c & 1][i] = *(const float4*)(
                    W + (size_t)(erowBase + (c + 2) * 32 + wave * 4 + i) * NDIM + bcol);
        }
    }
#undef STAGE
#undef COMPUTE
}

extern "C" void kernel_launch(void* const* d_in, const int* in_sizes, int n_in,
                              void* d_out, int out_size, void* d_ws, size_t ws_size,
                              hipStream_t stream) {
    const float* weight = (const float*)d_in[0];
    const float* dw     = (const float*)d_in[1];
    const int*   fidx   = (const int*)d_in[2];
    float* out = (float*)d_out;

    char* ws = (char*)d_ws;
    unsigned short* U = (unsigned short*)ws;                       // 6,291,456 B
    unsigned short* V = (unsigned short*)(ws + 6291456);           // 6,291,456 B

    fill_uv<<<16 * 96 * 2, 256, 0, stream>>>(fidx, weight ? (const float*)d_in[1] : (const float*)d_in[1], U, V);
    gemm_kernel<<<256, 512, 0, stream>>>(weight, U, V, out);
}

// Round 12
// 48.886 us; speedup vs baseline: 4.3770x; 1.0491x over previous
//
#include <hip/hip_runtime.h>

#define MDIM 4096
#define NDIM 4096
#define NCOEF 768
#define ALPHA 16.0f
#define PANEL_U16 (96 * 256 * 8)   // u16 per 256-row panel

typedef __attribute__((ext_vector_type(8))) short bf16x8;
typedef __attribute__((ext_vector_type(4))) float f32x4;

__device__ __forceinline__ unsigned short f2bf(float x) {
    unsigned u = __float_as_uint(x);
    u += 0x7FFFu + ((u >> 16) & 1u);
    return (unsigned short)(u >> 16);
}

__device__ __forceinline__ void glds16(const unsigned short* src, unsigned short* dst) {
    __builtin_amdgcn_global_load_lds(
        (const __attribute__((address_space(1))) void*)src,
        (__attribute__((address_space(3))) void*)dst, 16, 0, 0);
}

// ---- kernel 1 (meta fused): materialize U,V in 256-row PANEL layout ----
// U[((panel*96 + kc)*256 + row)*8 + pi]; i = panel*256+row, p = kc*8+pi.
// Dedup (last-write-wins) per block: 32 threads per coef scan 24 q's each.
// cos via v_cos_f32 (revolutions), integer-exact range reduction.
__global__ __launch_bounds__(256) void fill_uv(
    const int* __restrict__ fidx, const float* __restrict__ dw,
    unsigned short* __restrict__ U, unsigned short* __restrict__ V)
{
    __shared__ int idx_s[NCOEF];
    __shared__ int dup[8];
    const int b = blockIdx.x;            // (panel*96 + kc)*2 + half
    const int half = b & 1;
    const int pk = b >> 1;               // panel*96 + kc
    const int panel = pk / 96;
    const int kc = pk - panel * 96;
    const int t = threadIdx.x;
    #pragma unroll
    for (int j = 0; j < 3; ++j) idx_s[t + (j << 8)] = fidx[t + (j << 8)];
    if (t < 8) dup[t] = 0;
    __syncthreads();
    {   // dedup for this block's 8 coefs
        const int ci = t >> 5;                    // 0..7
        const int pci = (kc << 3) + ci;
        const int myidx = idx_s[pci];
        const int q0 = (t & 31) * 24;             // 32 segments x 24 = 768
        int found = 0;
        #pragma unroll
        for (int s = 0; s < 24; ++s) {
            const int q = q0 + s;
            found |= (q > pci) & (idx_s[q] == myidx);
        }
        if (found) dup[ci] = 1;                   // benign same-value race
    }
    __syncthreads();
    const int rl = (half << 7) + (t >> 1);        // rowLocal 0..255
    const int row = (panel << 8) + rl;            // global i
    const int p0 = (kc << 3) + ((t & 1) << 2);
    const unsigned tt = 2u * (unsigned)row + 1u;
    const float wrev = 1.0f / 16384.0f;
    const float s0 = 0.015625f;                   // sqrt(1/4096)
    const float s1 = 0.022097086912079612f;       // sqrt(2/4096)
    unsigned short uo[4], vo[4];
    #pragma unroll
    for (int j = 0; j < 4; ++j) {
        const int p = p0 + j;
        const int idx = idx_s[p];
        const int r = idx >> 12;
        const int c = idx & (NDIM - 1);
        const float su = (r == 0) ? s0 : s1;
        const float sv = (dup[p - (kc << 3)] ? 0.0f : 1.0f) * ALPHA * dw[p]
                         * ((c == 0) ? s0 : s1);
        const unsigned nu = (tt * (unsigned)r) & 16383u;
        const unsigned nv = (tt * (unsigned)c) & 16383u;
        uo[j] = f2bf(su * __builtin_amdgcn_cosf((float)nu * wrev));
        vo[j] = f2bf(sv * __builtin_amdgcn_cosf((float)nv * wrev));
    }
    const size_t o = ((size_t)pk * 256 + rl) * 8 + ((t & 1) << 2);
    *(ushort4*)(U + o) = *(const ushort4*)uo;
    *(ushort4*)(V + o) = *(const ushort4*)vo;
}

// ---- kernel 2: out = W + U @ V^T  (M=N=4096, K=768) ----
// 256x128 tile, 4 waves (2x2), BK=32, 24 iters, 2-buf 48 KB LDS -> 2-3
// blocks CO-RESIDENT per CU: one block's HBM-heavy epilogue overlaps the
// sibling's LDS/MFMA-heavy K-loop; barrier stalls backfill across blocks.
// Per-wave output 128x64 (8x4 frags), swapped mfma(b,a) -> float4 epilogue
// via pipelined LDS transpose (8 chunks of 32 rows, raw barriers, W
// prefetched depth-1; chunk-0 W issued inside K-loop with exact vmcnt).
__global__ __launch_bounds__(256, 2) void gemm_kernel(
    const float* __restrict__ W,
    const unsigned short* __restrict__ U,
    const unsigned short* __restrict__ V,
    float* __restrict__ out)
{
    __shared__ unsigned short SM[24576];   // 48 KB
    unsigned short* const As = SM;         // bufs: 0, 8192 (u16)
    unsigned short* const Bs = SM + 16384; // bufs: +0, +4096 (u16)

    const int tid = threadIdx.x;           // 0..255
    const int lane = tid & 63;
    const int wave = tid >> 6;              // 0..3

    // XCD rect swizzle: 512 blocks, 8 XCDs, rect 4(by) x 16(bx) per XCD.
    const int bid = blockIdx.x;
    const int xcd = bid & 7;
    const int local = bid >> 3;                        // 0..63
    const int by = ((xcd >> 1) << 2) + (local >> 4);   // 0..15 (256-row)
    const int bx = ((xcd & 1) << 4) + (local & 15);    // 0..31 (128-col)
    const int wr = wave >> 1;               // 0..1
    const int wc = wave & 1;                // 0..1
    const int fr = lane & 15;
    const int fks = lane >> 4;

    const unsigned short* uPan = U + (size_t)by * PANEL_U16;
    // V half-panel fold: chunk (kc*256 + (bx&1)*128 + rl) -> linear +1024 u16
    const unsigned short* vBase = V + (size_t)(bx >> 1) * PANEL_U16
                                    + (size_t)(bx & 1) * 1024;

    f32x4 acc[8][4] = {};

    // LDS read offsets (u16)
    const int aO = (((fks << 8) + wr * 128 + fr) << 3);   // chunk*8
    const int bO = (((fks << 7) + wc * 64 + fr) << 3);

    // epilogue coords
    const int bcol = bx << 7;
    const int erowBase = by << 8;
    float4 wpre[2][4];

    // A stage: 16 KB slab contiguous; chunk c = q*256+tid, q 0..3
    // B stage: 8 KB; chunk c = q*256+tid, q 0..1; src has kc-fold (+1024/kc)
#define STAGE(j, buf) do {                                                   \
        const unsigned short* uS = uPan + (size_t)(j) * 8192;                \
        const unsigned short* vS = vBase + (size_t)(j) * 8192;               \
        _Pragma("unroll")                                                    \
        for (int q = 0; q < 4; ++q)                                          \
            glds16(uS + (((q << 8) + tid) << 3),                             \
                   &As[(buf) * 8192 + ((q << 11) + (wave << 9))]);           \
        _Pragma("unroll")                                                    \
        for (int q = 0; q < 2; ++q) {                                        \
            const int c = (q << 8) + tid;                                    \
            glds16(vS + ((c + ((c >> 7) << 7)) << 3),                        \
                   &Bs[(buf) * 4096 + ((q << 11) + (wave << 9))]);           \
        }                                                                    \
    } while (0)

#define COMPUTE(buf) do {                                                    \
        bf16x8 a[8], b[4];                                                   \
        _Pragma("unroll")                                                    \
        for (int fm = 0; fm < 8; ++fm)                                       \
            a[fm] = *(const bf16x8*)&As[(buf) * 8192 + aO + (fm << 7)];      \
        _Pragma("unroll")                                                    \
        for (int fn = 0; fn < 4; ++fn)                                       \
            b[fn] = *(const bf16x8*)&Bs[(buf) * 4096 + bO + (fn << 7)];      \
        _Pragma("unroll")                                                    \
        for (int fm = 0; fm < 8; ++fm)                                       \
            _Pragma("unroll")                                                \
            for (int fn = 0; fn < 4; ++fn)                                   \
                acc[fm][fn] = __builtin_amdgcn_mfma_f32_16x16x32_bf16(       \
                    b[fn], a[fm], acc[fm][fn], 0, 0, 0);                     \
    } while (0)

    STAGE(0, 0);
    #pragma unroll
    for (int j = 0; j < 24; ++j) {
        if (j < 23) STAGE(j + 1, (j + 1) & 1);
        if (j == 22) {
            // W prefetch for epilogue chunk 0 (4 loads, counted below)
            #pragma unroll
            for (int i = 0; i < 4; ++i) {
                const int idx = (i << 8) + tid;
                wpre[0][i] = *(const float4*)(
                    W + (size_t)(erowBase + (idx >> 5)) * NDIM + bcol + ((idx & 31) << 2));
            }
        }
        // wait stage j complete; leave stage j+1 (6) [+ 4 W from j>=22]
        if (j < 22)       asm volatile("s_waitcnt vmcnt(6)"  ::: "memory");
        else if (j == 22) asm volatile("s_waitcnt vmcnt(10)" ::: "memory");
        else              asm volatile("s_waitcnt vmcnt(4)"  ::: "memory");
        __builtin_amdgcn_s_barrier();
        asm volatile("" ::: "memory");
        COMPUTE(j & 1);
        if (j < 23) {
            asm volatile("s_waitcnt lgkmcnt(0)" ::: "memory");
            __builtin_amdgcn_s_barrier();
            asm volatile("" ::: "memory");
        }
    }

    // ---- epilogue: out = W + acc, pipelined LDS transpose ----
    // acc[fm][fn][jj] = tile[wr*128 + fm*16 + fr][wc*64 + fn*16 + fks*4 + jj]
    // chunk c (0..7): rows 32c..32c+31, owner wr == c>>2, acc pair (c&3)*2.
    // L: 32 rows x 132 f32 = 16.9 KB (overlaps As; guarded by barriers).
    float* const L = (float*)SM;
    #pragma unroll
    for (int c = 0; c < 8; ++c) {
        asm volatile("s_waitcnt lgkmcnt(0)" ::: "memory");
        __builtin_amdgcn_s_barrier();      // L free (prev reads / last COMPUTE done)
        asm volatile("" ::: "memory");
        if (wr == (c >> 2)) {
            #pragma unroll
            for (int f2 = 0; f2 < 2; ++f2)
                #pragma unroll
                for (int fn = 0; fn < 4; ++fn)
                    *(f32x4*)(L + (f2 * 16 + fr) * 132 + wc * 64 + fn * 16 + fks * 4)
                        = acc[(c & 3) * 2 + f2][fn];
        }
        if (c < 7) {   // W for chunk c+1; stays in flight across raw barriers
            #pragma unroll
            for (int i = 0; i < 4; ++i) {
                const int idx = (i << 8) + tid;
                wpre[(c + 1) & 1][i] = *(const float4*)(
                    W + (size_t)(erowBase + (c + 1) * 32 + (idx >> 5)) * NDIM
                      + bcol + ((idx & 31) << 2));
            }
        }
        asm volatile("s_waitcnt lgkmcnt(0)" ::: "memory");
        __builtin_amdgcn_s_barrier();      // L visible
        asm volatile("" ::: "memory");
        #pragma unroll
        for (int i = 0; i < 4; ++i) {
            const int idx = (i << 8) + tid;
            const int rl = idx >> 5;
            const int c4 = (idx & 31) << 2;
            const size_t o = (size_t)(erowBase + c * 32 + rl) * NDIM + bcol + c4;
            const f32x4 l4 = *(const f32x4*)(L + rl * 132 + c4);
            float4 r4;
            r4.x = wpre[c & 1][i].x + l4[0];
            r4.y = wpre[c & 1][i].y + l4[1];
            r4.z = wpre[c & 1][i].z + l4[2];
            r4.w = wpre[c & 1][i].w + l4[3];
            *(float4*)(out + o) = r4;
        }
    }
#undef STAGE
#undef COMPUTE
}

extern "C" void kernel_launch(void* const* d_in, const int* in_sizes, int n_in,
                              void* d_out, int out_size, void* d_ws, size_t ws_size,
                              hipStream_t stream) {
    const float* weight = (const float*)d_in[0];
    const float* dw     = (const float*)d_in[1];
    const int*   fidx   = (const int*)d_in[2];
    float* out = (float*)d_out;

    char* ws = (char*)d_ws;
    unsigned short* U = (unsigned short*)ws;                       // 6,291,456 B
    unsigned short* V = (unsigned short*)(ws + 6291456);           // 6,291,456 B

    fill_uv<<<16 * 96 * 2, 256, 0, stream>>>(fidx, dw, U, V);
    gemm_kernel<<<512, 256, 0, stream>>>(weight, U, V, out);
}